// Round 2
// baseline (33159.497 us; speedup 1.0000x reference)
//
#include <hip/hip_runtime.h>
#include <stdint.h>

// LSTM seq2seq. Inputs/outputs are FLOAT32 (per the reference); harness tolerance is
// bf16-grade (2% of max|ref|), so internal compute uses bf16 MFMA + fp32 c-state.
//
// Design: grid=256 blocks (== CU count, co-resident), batch x hidden 2D partitioning so
// sync scope is a batch-tile group only.
// Encoder: 8 batch-tiles(32 rows) x 32 hidden-slices(8 hid), layer-pipelined -> 1 barrier/step.
// Decoder: 32 batch-tiles(128 rows) x 8 hidden-slices(32 hid), 2 barriers/step (feedback).
// h exchanged via global bf16 double buffers + device-scope fenced counter barriers.
// Decoder weights pre-converted f32->bf16 into workspace by cvt_kernel.

typedef short short8v __attribute__((ext_vector_type(8)));
typedef float float4v __attribute__((ext_vector_type(4)));

#define MFMA(a, b, c) __builtin_amdgcn_mfma_f32_16x16x32_bf16((a), (b), (c), 0, 0, 0)

#define HIDN 256
#define TLEN 512
#define DB   4096   /* decoder batch = 16*256 */

__device__ __forceinline__ unsigned short f2b(float f) {
    unsigned int u = __float_as_uint(f);
    unsigned int r = ((u >> 16) & 1u) + 0x7FFFu;
    return (unsigned short)((u + r) >> 16);
}
__device__ __forceinline__ float sigf(float x) { return 1.0f / (1.0f + __expf(-x)); }
__device__ __forceinline__ float tanhf2(float x) { return 1.0f - 2.0f / (1.0f + __expf(2.0f * x)); }

// Group barrier: monotonic counter, release add + relaxed spin + acquire fence.
// Bounded spin so a residency failure degrades to wrong-answer instead of hang.
__device__ __forceinline__ void group_barrier(unsigned int* c, unsigned int target,
                                              int tid, int& dead) {
    __threadfence();          // release: push my h writes to device coherence point
    __syncthreads();
    if (tid == 0) {
        __hip_atomic_fetch_add(c, 1u, __ATOMIC_RELEASE, __HIP_MEMORY_SCOPE_AGENT);
        if (!dead) {
            int guard = 0;
            while (__hip_atomic_load(c, __ATOMIC_RELAXED, __HIP_MEMORY_SCOPE_AGENT) < target) {
                __builtin_amdgcn_s_sleep(1);
                if (++guard > (1 << 21)) { dead = 1; break; }
            }
        }
    }
    __syncthreads();
    __threadfence();          // acquire: invalidate caches for fresh h reads
}

// f32 -> bf16 conversion of the three decoder matrices (each [1024][256]).
__global__ __launch_bounds__(256) void cvt_kernel(const float* __restrict__ s0,
                                                  const float* __restrict__ s1,
                                                  const float* __restrict__ s2,
                                                  unsigned short* __restrict__ d) {
    int m = blockIdx.x >> 8;                             // 0..2
    int i = ((blockIdx.x & 255) * 256 + threadIdx.x) * 4; // element index, 262144 per matrix
    const float* s = (m == 0) ? s0 : (m == 1) ? s1 : s2;
    float4 v = *(const float4*)&s[i];
    unsigned short o[4] = {f2b(v.x), f2b(v.y), f2b(v.z), f2b(v.w)};
    *(uint64_t*)&d[m * 262144 + i] = *(const uint64_t*)o;
}

// ============================ ENCODER ============================
// grid 256 = 8 bt (32 rows) x 32 hs (8 hid -> 32 gate rows). Weight slices bf16 in LDS.
// Super-step s: layer0 t=s (s<=512), layer1 t=s-1 (s>=2). Both read parity (s-1)&1,
// write parity s&1. 513 super-steps, 1 barrier each.
__global__ __launch_bounds__(256) void enc_kernel(
    const float* __restrict__ x,
    const float* __restrict__ Wih0,
    const float* __restrict__ Whh0,
    const float* __restrict__ b0,
    const float* __restrict__ Wih1,
    const float* __restrict__ Whh1,
    const float* __restrict__ b1,
    unsigned short* __restrict__ h0buf,   // [2][4096][256] bf16 (rows 0..255 used)
    unsigned short* __restrict__ h1buf,
    unsigned short* __restrict__ finh0,   // [256][256] bf16
    unsigned short* __restrict__ finh1,
    float* __restrict__ finc0,            // [256][256] f32
    float* __restrict__ finc1,
    unsigned int* __restrict__ ctr)       // 8 groups, stride 16 uints
{
    const int tid  = threadIdx.x;
    const int bt   = blockIdx.x >> 5;
    const int hs   = blockIdx.x & 31;
    const int row0 = bt << 5;          // *32
    const int hid0 = hs << 3;          // *8

    __shared__ unsigned short lw[3][32][264];  // Whh0, Wih1, Whh1 slices; rows [i8,f8,g8,o8]
    __shared__ float gt[2][32][33];            // gates tiles layer0/layer1

    {
        const float* srcs[3] = {Whh0, Wih1, Whh1};
        for (int mat = 0; mat < 3; ++mat) {
            const float* W = srcs[mat];
            for (int idx = tid; idx < 32 * 64; idx += 256) {
                int m  = idx >> 6;
                int c4 = (idx & 63) << 2;
                int g  = ((m >> 3) << 8) + hid0 + (m & 7);   // gate row: type*256 + hid
                float4 v = *(const float4*)&W[g * HIDN + c4];
                lw[mat][m][c4 + 0] = f2b(v.x);
                lw[mat][m][c4 + 1] = f2b(v.y);
                lw[mat][m][c4 + 2] = f2b(v.z);
                lw[mat][m][c4 + 3] = f2b(v.w);
            }
        }
    }
    __syncthreads();

    const int lane = tid & 63;
    const int wv   = tid >> 6;
    const int mi   = (wv >> 1) << 4;
    const int ni   = (wv & 1) << 4;
    const int l15  = lane & 15;
    const int q8   = (lane >> 4) << 3;
    const int crow = ((lane >> 4) << 2);

    const int erow = tid >> 3;   // 0..31
    const int ehid = tid & 7;    // 0..7
    float wx[4], bb0v[4], bb1v[4];
#pragma unroll
    for (int k2 = 0; k2 < 4; ++k2) {
        int g = (k2 << 8) + hid0 + ehid;
        wx[k2]   = Wih0[g];
        bb0v[k2] = b0[g];
        bb1v[k2] = b1[g];
    }
    float c0 = 0.f, c1 = 0.f;
    const int xrow = row0 + erow;
    int dead = 0;

    for (int s = 1; s <= 513; ++s) {
        const unsigned short* hr0 = h0buf + ((size_t)((s - 1) & 1) * DB * HIDN);
        const unsigned short* hr1 = h1buf + ((size_t)((s - 1) & 1) * DB * HIDN);
        unsigned short* hw0 = h0buf + ((size_t)(s & 1) * DB * HIDN);
        unsigned short* hw1 = h1buf + ((size_t)(s & 1) * DB * HIDN);

        float4v acc0 = {0.f, 0.f, 0.f, 0.f};
        float4v acc1 = {0.f, 0.f, 0.f, 0.f};
        const int arow = (row0 + mi + l15) * HIDN + q8;

        if (s > 1 && s <= 512) {   // layer0: h0(s-1) @ Whh0^T   (h0(0)=0 -> skip at s=1)
#pragma unroll
            for (int kc = 0; kc < 8; ++kc) {
                short8v a = *(const short8v*)&hr0[arow + (kc << 5)];
                short8v b = *(const short8v*)&lw[0][ni + l15][(kc << 5) + q8];
                acc0 = MFMA(a, b, acc0);
            }
        }
        if (s >= 2) {              // layer1 t=s-1: h0(s-1)@Wih1^T + h1(s-2)@Whh1^T
#pragma unroll
            for (int kc = 0; kc < 8; ++kc) {
                short8v a = *(const short8v*)&hr0[arow + (kc << 5)];
                short8v b = *(const short8v*)&lw[1][ni + l15][(kc << 5) + q8];
                acc1 = MFMA(a, b, acc1);
            }
            if (s >= 3) {          // h1(0)=0 -> skip at s=2
#pragma unroll
                for (int kc = 0; kc < 8; ++kc) {
                    short8v a = *(const short8v*)&hr1[arow + (kc << 5)];
                    short8v b = *(const short8v*)&lw[2][ni + l15][(kc << 5) + q8];
                    acc1 = MFMA(a, b, acc1);
                }
            }
        }
#pragma unroll
        for (int r = 0; r < 4; ++r) {   // C/D: row=(lane>>4)*4+r, col=lane&15
            gt[0][mi + crow + r][ni + l15] = acc0[r];
            gt[1][mi + crow + r][ni + l15] = acc1[r];
        }
        __syncthreads();

        if (s <= 512) {
            float xv = x[xrow * TLEN + (s - 1)];
            float gi = gt[0][erow][ehid]      + wx[0] * xv + bb0v[0];
            float gf = gt[0][erow][8 + ehid]  + wx[1] * xv + bb0v[1];
            float gg = gt[0][erow][16 + ehid] + wx[2] * xv + bb0v[2];
            float go = gt[0][erow][24 + ehid] + wx[3] * xv + bb0v[3];
            c0 = sigf(gf) * c0 + sigf(gi) * tanhf2(gg);
            float h0n = sigf(go) * tanhf2(c0);
            hw0[(row0 + erow) * HIDN + hid0 + ehid] = f2b(h0n);
            if (s == 512) {
                finh0[(row0 + erow) * HIDN + hid0 + ehid] = f2b(h0n);
                finc0[(row0 + erow) * HIDN + hid0 + ehid] = c0;
            }
        }
        if (s >= 2) {
            float gi = gt[1][erow][ehid]      + bb1v[0];
            float gf = gt[1][erow][8 + ehid]  + bb1v[1];
            float gg = gt[1][erow][16 + ehid] + bb1v[2];
            float go = gt[1][erow][24 + ehid] + bb1v[3];
            c1 = sigf(gf) * c1 + sigf(gi) * tanhf2(gg);
            float h1n = sigf(go) * tanhf2(c1);
            hw1[(row0 + erow) * HIDN + hid0 + ehid] = f2b(h1n);
            if (s == 513) {
                finh1[(row0 + erow) * HIDN + hid0 + ehid] = f2b(h1n);
                finc1[(row0 + erow) * HIDN + hid0 + ehid] = c1;
            }
        }
        group_barrier(ctr + bt * 16, (unsigned)(32 * s), tid, dead);
    }
}

// ============================ DECODER ============================
// grid 256 = 32 bt (128 rows) x 8 hs (32 hid -> 128 gate rows). bf16 weights from L2.
// Per step: phase A (layer0, reads pred(t-1)) | barrier | phase B (layer1 + pred) | barrier.
__global__ __launch_bounds__(256) void dec_kernel(
    const float* __restrict__ Wih0,
    const unsigned short* __restrict__ Whh0,   // bf16, converted
    const float* __restrict__ b0,
    const unsigned short* __restrict__ Wih1,   // bf16, converted
    const unsigned short* __restrict__ Whh1,   // bf16, converted
    const float* __restrict__ b1,
    const float* __restrict__ outW,
    const float* __restrict__ outb,
    const float* __restrict__ dinit,           // [4096] f32
    const unsigned short* __restrict__ finh0,
    const unsigned short* __restrict__ finh1,
    const float* __restrict__ finc0,
    const float* __restrict__ finc1,
    unsigned short* __restrict__ h0buf,        // [2][4096][256] bf16
    unsigned short* __restrict__ h1buf,
    float* __restrict__ predbuf,               // [2][4096] f32 (no out_b)
    float* __restrict__ out,                   // [256][16][64] f32
    unsigned int* __restrict__ ctr)            // 32 groups, stride 16 uints
{
    const int tid  = threadIdx.x;
    const int bt   = blockIdx.x >> 3;   // 0..31
    const int hs   = blockIdx.x & 7;    // 0..7
    const int row0 = bt << 7;           // *128
    const int hid0 = hs << 5;           // *32

    __shared__ float gt[32][132];

    const int lane = tid & 63;
    const int wv   = tid >> 6;
    const int l15  = lane & 15;
    const int q8   = (lane >> 4) << 3;
    const int qr   = (lane >> 4) << 2;

    const int ehid = tid & 31;
    const int erb  = tid >> 5;          // 0..7
    const float outb_v = outb[0];
    const float outw_v = outW[hid0 + ehid];
    float wxd[4], bb0d[4], bb1d[4];
#pragma unroll
    for (int k2 = 0; k2 < 4; ++k2) {
        int g = (k2 << 8) + hid0 + ehid;
        wxd[k2]  = Wih0[g];
        bb0d[k2] = b0[g];
        bb1d[k2] = b1[g];
    }

    float c0r[16], c1r[16];
#pragma unroll
    for (int ch = 0; ch < 4; ++ch)
#pragma unroll
        for (int kk = 0; kk < 4; ++kk) {
            int r = row0 + (ch << 5) + (kk << 3) + erb;
            c0r[(ch << 2) + kk] = finc0[(r & 255) * HIDN + hid0 + ehid];
            c1r[(ch << 2) + kk] = finc1[(r & 255) * HIDN + hid0 + ehid];
        }

    // wave wv covers n_local in [wv*32, wv*32+32); gate row = type*256 + hid0 + (n_local&31)
    const int nl0 = (wv << 5) + l15;
    const int nl1 = nl0 + 16;
    const int g0  = ((nl0 >> 5) << 8) + hid0 + (nl0 & 31);
    const int g1  = ((nl1 >> 5) << 8) + hid0 + (nl1 & 31);
    int dead = 0;

    for (int t = 0; t < 64; ++t) {
        const unsigned short* h0rd = h0buf + ((size_t)((t + 1) & 1) * DB * HIDN);
        unsigned short* h0wr       = h0buf + ((size_t)(t & 1) * DB * HIDN);
        const unsigned short* h1rd = h1buf + ((size_t)((t + 1) & 1) * DB * HIDN);
        unsigned short* h1wr       = h1buf + ((size_t)(t & 1) * DB * HIDN);
        float* pw       = predbuf + (t & 1) * DB;
        const float* pr = predbuf + ((t + 1) & 1) * DB;

        // phase A pre: zero this step's pred accum; emit output column t-1
        if (hs == 0 && tid < 128) {
            int n = row0 + tid;
            pw[n] = 0.f;
            if (t > 0) {
                float pv = pr[n] + outb_v;
                out[(((n & 255) << 4) + (n >> 8)) * 64 + (t - 1)] = pv;
            }
        }

        // ---- phase A: layer0 ----
        for (int ch = 0; ch < 4; ++ch) {
            const int crow = row0 + (ch << 5);
            float4v a00 = {0,0,0,0}, a01 = {0,0,0,0}, a10 = {0,0,0,0}, a11 = {0,0,0,0};
#pragma unroll
            for (int kc = 0; kc < 8; ++kc) {
                short8v av0, av1;
                if (t == 0) {
                    av0 = *(const short8v*)&finh0[((crow + l15) & 255) * HIDN + (kc << 5) + q8];
                    av1 = *(const short8v*)&finh0[((crow + 16 + l15) & 255) * HIDN + (kc << 5) + q8];
                } else {
                    av0 = *(const short8v*)&h0rd[(crow + l15) * HIDN + (kc << 5) + q8];
                    av1 = *(const short8v*)&h0rd[(crow + 16 + l15) * HIDN + (kc << 5) + q8];
                }
                short8v bv0 = *(const short8v*)&Whh0[g0 * HIDN + (kc << 5) + q8];
                short8v bv1 = *(const short8v*)&Whh0[g1 * HIDN + (kc << 5) + q8];
                a00 = MFMA(av0, bv0, a00); a01 = MFMA(av0, bv1, a01);
                a10 = MFMA(av1, bv0, a10); a11 = MFMA(av1, bv1, a11);
            }
#pragma unroll
            for (int r = 0; r < 4; ++r) {
                gt[qr + r][(wv << 5) + l15]           = a00[r];
                gt[qr + r][(wv << 5) + 16 + l15]      = a01[r];
                gt[16 + qr + r][(wv << 5) + l15]      = a10[r];
                gt[16 + qr + r][(wv << 5) + 16 + l15] = a11[r];
            }
            __syncthreads();
#pragma unroll
            for (int kk = 0; kk < 4; ++kk) {
                int rowl = (kk << 3) + erb;
                int rg   = crow + rowl;
                float inpv = (t == 0) ? dinit[rg] : (pr[rg] + outb_v);
                float gi = gt[rowl][ehid]      + wxd[0] * inpv + bb0d[0];
                float gf = gt[rowl][32 + ehid] + wxd[1] * inpv + bb0d[1];
                float gg = gt[rowl][64 + ehid] + wxd[2] * inpv + bb0d[2];
                float go = gt[rowl][96 + ehid] + wxd[3] * inpv + bb0d[3];
                int ci = (ch << 2) + kk;
                c0r[ci] = sigf(gf) * c0r[ci] + sigf(gi) * tanhf2(gg);
                float h0n = sigf(go) * tanhf2(c0r[ci]);
                h0wr[rg * HIDN + hid0 + ehid] = f2b(h0n);
            }
            __syncthreads();
        }
        group_barrier(ctr + bt * 16, (unsigned)(16 * t + 8), tid, dead);

        // ---- phase B: layer1 + pred ----
        for (int ch = 0; ch < 4; ++ch) {
            const int crow = row0 + (ch << 5);
            float4v a00 = {0,0,0,0}, a01 = {0,0,0,0}, a10 = {0,0,0,0}, a11 = {0,0,0,0};
#pragma unroll
            for (int kc = 0; kc < 8; ++kc) {   // h0(t) @ Wih1^T
                short8v av0 = *(const short8v*)&h0wr[(crow + l15) * HIDN + (kc << 5) + q8];
                short8v av1 = *(const short8v*)&h0wr[(crow + 16 + l15) * HIDN + (kc << 5) + q8];
                short8v bv0 = *(const short8v*)&Wih1[g0 * HIDN + (kc << 5) + q8];
                short8v bv1 = *(const short8v*)&Wih1[g1 * HIDN + (kc << 5) + q8];
                a00 = MFMA(av0, bv0, a00); a01 = MFMA(av0, bv1, a01);
                a10 = MFMA(av1, bv0, a10); a11 = MFMA(av1, bv1, a11);
            }
#pragma unroll
            for (int kc = 0; kc < 8; ++kc) {   // h1(t-1) @ Whh1^T
                short8v av0, av1;
                if (t == 0) {
                    av0 = *(const short8v*)&finh1[((crow + l15) & 255) * HIDN + (kc << 5) + q8];
                    av1 = *(const short8v*)&finh1[((crow + 16 + l15) & 255) * HIDN + (kc << 5) + q8];
                } else {
                    av0 = *(const short8v*)&h1rd[(crow + l15) * HIDN + (kc << 5) + q8];
                    av1 = *(const short8v*)&h1rd[(crow + 16 + l15) * HIDN + (kc << 5) + q8];
                }
                short8v bv0 = *(const short8v*)&Whh1[g0 * HIDN + (kc << 5) + q8];
                short8v bv1 = *(const short8v*)&Whh1[g1 * HIDN + (kc << 5) + q8];
                a00 = MFMA(av0, bv0, a00); a01 = MFMA(av0, bv1, a01);
                a10 = MFMA(av1, bv0, a10); a11 = MFMA(av1, bv1, a11);
            }
#pragma unroll
            for (int r = 0; r < 4; ++r) {
                gt[qr + r][(wv << 5) + l15]           = a00[r];
                gt[qr + r][(wv << 5) + 16 + l15]      = a01[r];
                gt[16 + qr + r][(wv << 5) + l15]      = a10[r];
                gt[16 + qr + r][(wv << 5) + 16 + l15] = a11[r];
            }
            __syncthreads();
#pragma unroll
            for (int kk = 0; kk < 4; ++kk) {
                int rowl = (kk << 3) + erb;
                int rg   = crow + rowl;
                float gi = gt[rowl][ehid]      + bb1d[0];
                float gf = gt[rowl][32 + ehid] + bb1d[1];
                float gg = gt[rowl][64 + ehid] + bb1d[2];
                float go = gt[rowl][96 + ehid] + bb1d[3];
                int ci = (ch << 2) + kk;
                c1r[ci] = sigf(gf) * c1r[ci] + sigf(gi) * tanhf2(gg);
                float h1n = sigf(go) * tanhf2(c1r[ci]);
                h1wr[rg * HIDN + hid0 + ehid] = f2b(h1n);
                float pp = h1n * outw_v;
#pragma unroll
                for (int off = 16; off > 0; off >>= 1) pp += __shfl_xor(pp, off, 64);
                if (ehid == 0) atomicAdd(&pw[rg], pp);
            }
            __syncthreads();
        }
        group_barrier(ctr + bt * 16, (unsigned)(16 * t + 16), tid, dead);
    }
    // tail: output column 63
    if (hs == 0 && tid < 128) {
        int n = row0 + tid;
        float pv = predbuf[DB + n] + outb_v;   // t=63 parity 1
        out[(((n & 255) << 4) + (n >> 8)) * 64 + 63] = pv;
    }
}

extern "C" void kernel_launch(void* const* d_in, const int* in_sizes, int n_in,
                              void* d_out, int out_size, void* d_ws, size_t ws_size,
                              hipStream_t stream) {
    (void)in_sizes; (void)n_in; (void)out_size; (void)ws_size;
    const float* x     = (const float*)d_in[0];
    const float* eWih0 = (const float*)d_in[1];
    const float* eWhh0 = (const float*)d_in[2];
    const float* eb0   = (const float*)d_in[3];
    const float* eWih1 = (const float*)d_in[4];
    const float* eWhh1 = (const float*)d_in[5];
    const float* eb1   = (const float*)d_in[6];
    const float* dWih0 = (const float*)d_in[7];
    const float* dWhh0 = (const float*)d_in[8];
    const float* db0   = (const float*)d_in[9];
    const float* dWih1 = (const float*)d_in[10];
    const float* dWhh1 = (const float*)d_in[11];
    const float* db1   = (const float*)d_in[12];
    const float* outW  = (const float*)d_in[13];
    const float* outb  = (const float*)d_in[14];
    const float* dinit = (const float*)d_in[15];

    char* ws = (char*)d_ws;
    unsigned short* h0buf = (unsigned short*)(ws);                 // 4 MB
    unsigned short* h1buf = (unsigned short*)(ws + 4194304);       // 4 MB
    unsigned short* finh0 = (unsigned short*)(ws + 8388608);       // 128 KB
    unsigned short* finh1 = (unsigned short*)(ws + 8519680);       // 128 KB
    float* finc0          = (float*)(ws + 8650752);                // 256 KB
    float* finc1          = (float*)(ws + 8912896);                // 256 KB
    float* predbuf        = (float*)(ws + 9175040);                // 32 KB
    unsigned int* ctre    = (unsigned int*)(ws + 9207808);         // enc counters
    unsigned int* ctrd    = (unsigned int*)(ws + 9207808 + 4096);  // dec counters
    unsigned short* dwb   = (unsigned short*)(ws + 9216000);       // 1.5 MB bf16 dec weights

    hipMemsetAsync(ws + 9207808, 0, 8192, stream);
    cvt_kernel<<<768, 256, 0, stream>>>(dWhh0, dWih1, dWhh1, dwb);
    enc_kernel<<<256, 256, 0, stream>>>(x, eWih0, eWhh0, eb0, eWih1, eWhh1, eb1,
                                        h0buf, h1buf, finh0, finh1, finc0, finc1, ctre);
    dec_kernel<<<256, 256, 0, stream>>>(dWih0, dwb, db0, dwb + 262144, dwb + 524288, db1,
                                        outW, outb, dinit, finh0, finh1, finc0, finc1,
                                        h0buf, h1buf, predbuf, (float*)d_out, ctrd);
}

// Round 3
// 8282.468 us; speedup vs baseline: 4.0036x; 4.0036x over previous
//
#include <hip/hip_runtime.h>
#include <stdint.h>

// Seq2seq LSTM, f32 in/out, bf16 MFMA compute, fp32 cell state.
// Sync redesign vs R2: no __threadfence (was buffer_wbl2 + full inv each step).
// h exchanged via agent-scope relaxed atomic u32 stores (write-through to LLC),
// per-block flag slots + relaxed polling + one acquire load (buffer_inv only),
// then plain vector loads (L2 miss -> fresh from LLC).
// Encoder: 256 blocks = 16 batch-groups(16 rows) x 16 hid-slices(16 hid).
//   Weights in REGISTERS (3 (mat,gate) pairs/wave = 96 VGPRs), gates exchanged
//   via 13KB LDS tile, per-thread c-state, 1 barrier per super-step (513).
// Decoder: 256 blocks = 16 batch-groups(256 rows) x 16 hid-slices.
//   Weights fragment-packed in 96KB dynamic LDS (conflict-free ds_read_b128),
//   waves split M (64 rows), fully in-register epilogue, 2 barriers/step.
// blockIdx mapping (hs*16+bt) puts a group's 16 blocks on one XCD (perf only).

typedef short short8v __attribute__((ext_vector_type(8)));
typedef float float4v __attribute__((ext_vector_type(4)));
#define MFMA(a,b,c) __builtin_amdgcn_mfma_f32_16x16x32_bf16((a),(b),(c),0,0,0)

#define HIDN 256
#define TLEN 512
#define DB   4096
#define HP   ((size_t)DB * HIDN)   // elements per h parity buffer

__device__ __forceinline__ unsigned short f2b(float f) {
    unsigned int u = __float_as_uint(f);
    unsigned int r = ((u >> 16) & 1u) + 0x7FFFu;
    return (unsigned short)((u + r) >> 16);
}
__device__ __forceinline__ float sigf(float x) { return 1.0f / (1.0f + __expf(-x)); }
__device__ __forceinline__ float tanhf2(float x) { return 1.0f - 2.0f / (1.0f + __expf(2.0f * x)); }

// pack 2 adjacent-hid bf16 via lane^1 shuffle, even lane stores coherent u32
__device__ __forceinline__ void hpair_store(unsigned short* buf, int row, int hid,
                                            float h, int lane) {
    unsigned int mine = f2b(h);
    unsigned int part = (unsigned int)__shfl_xor((int)mine, 1);
    if (!(lane & 1)) {
        __hip_atomic_store((unsigned int*)&buf[row * HIDN + hid], mine | (part << 16),
                           __ATOMIC_RELAXED, __HIP_MEMORY_SCOPE_AGENT);
    }
}

// group barrier: my slot already stored (release-ish via s_barrier vmcnt drain);
// poll 16 slots with relaxed agent loads; final acquire load = buffer_inv.
__device__ __forceinline__ void group_wait(unsigned int* fl, unsigned int target,
                                           int lane, int& dead) {
    if (dead) return;
    int guard = 0;
    for (;;) {
        unsigned int v = 0xFFFFFFFFu;
        if (lane < 16) v = __hip_atomic_load(&fl[lane], __ATOMIC_RELAXED, __HIP_MEMORY_SCOPE_AGENT);
        if (__ballot(v >= target) == ~0ull) break;
        if (++guard > (1 << 19)) { dead = 1; break; }
        __builtin_amdgcn_s_sleep(1);
    }
    (void)__hip_atomic_load(&fl[0], __ATOMIC_ACQUIRE, __HIP_MEMORY_SCOPE_AGENT);
}

// ============================ ENCODER ============================
__global__ __launch_bounds__(256, 1) void enc_kernel(
    const float* __restrict__ x,
    const float* __restrict__ Wih0, const float* __restrict__ Whh0, const float* __restrict__ b0,
    const float* __restrict__ Wih1, const float* __restrict__ Whh1, const float* __restrict__ b1,
    unsigned short* __restrict__ h0buf, unsigned short* __restrict__ h1buf,
    float* __restrict__ finc0, float* __restrict__ finc1,
    unsigned int* __restrict__ flags)
{
    const int tid  = threadIdx.x;
    const int lane = tid & 63;
    const int wv   = tid >> 6;
    const int bt   = blockIdx.x & 15;   // group: 16 rows; XCD = bt%8
    const int hs   = blockIdx.x >> 4;   // hid slice: 16 hid
    const int row0 = bt << 4;
    const int hidb = hs << 4;
    const int l15  = lane & 15;
    const int q    = lane >> 4;
    const int q8   = q << 3;

    __shared__ float gt[12][16][17];    // gate tiles: pair p -> [row][hid]

    // register weights: wave wv owns pairs p = wv*3+j, p=(mat*4+gate)
    short8v wf[3][8];
    {
        const float* Ws[3] = {Whh0, Wih1, Whh1};
#pragma unroll
        for (int j = 0; j < 3; ++j) {
            int p = wv * 3 + j;
            int mat = p >> 2, g = p & 3;
            const float* W = Ws[mat];
            const float* rp = W + (size_t)((g << 8) + hidb + l15) * HIDN + q8;
#pragma unroll
            for (int kc = 0; kc < 8; ++kc) {
                short8v v;
#pragma unroll
                for (int i = 0; i < 8; ++i) v[i] = (short)f2b(rp[(kc << 5) + i]);
                wf[j][kc] = v;
            }
        }
    }
    const bool useH0 = (wv <= 2);            // pairs touching mats 0/1
    const bool useH1 = (wv >= 2);            // pairs touching mat 2

    // epilogue cell: thread -> (row, hid)
    const int erow = tid >> 4;
    const int ehid = tid & 15;
    const int grow = row0 + erow;
    const int ghid = hidb + ehid;
    float wx[4], bb0v[4], bb1v[4];
#pragma unroll
    for (int g = 0; g < 4; ++g) {
        wx[g]   = Wih0[(g << 8) + ghid];
        bb0v[g] = b0[(g << 8) + ghid];
        bb1v[g] = b1[(g << 8) + ghid];
    }
    float c0 = 0.f, c1 = 0.f;
    unsigned int* fl = flags + (bt << 4);
    int dead = 0;

    for (int s = 1; s <= 513; ++s) {
        const unsigned short* hr0 = h0buf + (size_t)((s - 1) & 1) * HP;
        const unsigned short* hr1 = h1buf + (size_t)((s - 1) & 1) * HP;
        unsigned short* hw0 = h0buf + (size_t)(s & 1) * HP;
        unsigned short* hw1 = h1buf + (size_t)(s & 1) * HP;

        float4v acc[3] = {{0,0,0,0},{0,0,0,0},{0,0,0,0}};
        short8v a0f[8], a1f[8];
        if (useH0 && s >= 2) {
            const unsigned short* p0 = hr0 + (size_t)(row0 + l15) * HIDN + q8;
#pragma unroll
            for (int kc = 0; kc < 8; ++kc) a0f[kc] = *(const short8v*)&p0[kc << 5];
        }
        if (useH1 && s >= 3) {
            const unsigned short* p1 = hr1 + (size_t)(row0 + l15) * HIDN + q8;
#pragma unroll
            for (int kc = 0; kc < 8; ++kc) a1f[kc] = *(const short8v*)&p1[kc << 5];
        }
#pragma unroll
        for (int j = 0; j < 3; ++j) {
            int p = wv * 3 + j;
            int mat = p >> 2;
            bool active = (mat == 0) ? (s >= 2 && s <= 512)
                        : (mat == 1) ? (s >= 2)
                                     : (s >= 3);
            if (active) {
                if (mat == 2) {
#pragma unroll
                    for (int kc = 0; kc < 8; ++kc) acc[j] = MFMA(a1f[kc], wf[j][kc], acc[j]);
                } else {
#pragma unroll
                    for (int kc = 0; kc < 8; ++kc) acc[j] = MFMA(a0f[kc], wf[j][kc], acc[j]);
                }
            }
        }
#pragma unroll
        for (int j = 0; j < 3; ++j) {
            int p = wv * 3 + j;
#pragma unroll
            for (int r = 0; r < 4; ++r) gt[p][(q << 2) + r][l15] = acc[j][r];
        }
        __syncthreads();

        if (s <= 512) {
            float xv = x[(size_t)grow * TLEN + (s - 1)];
            float gi = gt[0][erow][ehid] + wx[0] * xv + bb0v[0];
            float gf = gt[1][erow][ehid] + wx[1] * xv + bb0v[1];
            float gg = gt[2][erow][ehid] + wx[2] * xv + bb0v[2];
            float go = gt[3][erow][ehid] + wx[3] * xv + bb0v[3];
            c0 = sigf(gf) * c0 + sigf(gi) * tanhf2(gg);
            float h0n = sigf(go) * tanhf2(c0);
            hpair_store(hw0, grow, ghid, h0n, lane);
            if (s == 512) finc0[(size_t)grow * HIDN + ghid] = c0;
        }
        if (s >= 2) {
            float gi = gt[4][erow][ehid] + gt[8][erow][ehid]  + bb1v[0];
            float gf = gt[5][erow][ehid] + gt[9][erow][ehid]  + bb1v[1];
            float gg = gt[6][erow][ehid] + gt[10][erow][ehid] + bb1v[2];
            float go = gt[7][erow][ehid] + gt[11][erow][ehid] + bb1v[3];
            c1 = sigf(gf) * c1 + sigf(gi) * tanhf2(gg);
            float h1n = sigf(go) * tanhf2(c1);
            hpair_store(hw1, grow, ghid, h1n, lane);
            if (s == 513) finc1[(size_t)grow * HIDN + ghid] = c1;
        }
        __syncthreads();                       // drains vmcnt: h stores at LLC
        if (tid == 0)
            __hip_atomic_store(&fl[hs], (unsigned int)s, __ATOMIC_RELAXED, __HIP_MEMORY_SCOPE_AGENT);
        group_wait(fl, (unsigned int)s, lane, dead);
    }
}

// ============================ DECODER ============================
__global__ __launch_bounds__(256, 1) void dec_kernel(
    const float* __restrict__ Wih0, const float* __restrict__ Whh0, const float* __restrict__ b0,
    const float* __restrict__ Wih1, const float* __restrict__ Whh1, const float* __restrict__ b1,
    const float* __restrict__ outW, const float* __restrict__ outb,
    const float* __restrict__ dinit,
    const float* __restrict__ finc0, const float* __restrict__ finc1,
    unsigned short* __restrict__ h0buf, unsigned short* __restrict__ h1buf,
    float* __restrict__ predbuf, float* __restrict__ out,
    unsigned int* __restrict__ flags)
{
    extern __shared__ unsigned short wlds[];   // 3*4*8*64 frags * 16B = 96KB
    const int tid  = threadIdx.x;
    const int lane = tid & 63;
    const int wv   = tid >> 6;
    const int bt   = blockIdx.x & 15;   // group: 256 rows; XCD = bt%8
    const int hs   = blockIdx.x >> 4;   // hid slice: 16
    const int row0 = bt << 8;
    const int hidb = hs << 4;
    const int l15  = lane & 15;
    const int q    = lane >> 4;
    const int q8   = q << 3;
    const int hid  = hidb + l15;

    // fragment-packed weight preload: slot = ((mat*4+g)*8+kc)*64 + lane
    {
        for (int sl = tid; sl < 6144; sl += 256) {
            int mat = sl >> 11, g = (sl >> 9) & 3, kc = (sl >> 6) & 7, ln = sl & 63;
            const float* W = (mat == 0) ? Whh0 : ((mat == 1) ? Wih1 : Whh1);
            const float* p = W + (size_t)((g << 8) + hidb + (ln & 15)) * HIDN
                               + (kc << 5) + ((ln >> 4) << 3);
            short8v v;
#pragma unroll
            for (int i = 0; i < 8; ++i) v[i] = (short)f2b(p[i]);
            *(short8v*)&wlds[sl << 3] = v;
        }
    }
    __syncthreads();
#define WFRAG(mat, g, kc) (*(const short8v*)&wlds[((((((mat) << 2) + (g)) << 3) + (kc)) << 9) + (lane << 3)])

    float wx[4], bb0v[4], bb1v[4];
#pragma unroll
    for (int g = 0; g < 4; ++g) {
        wx[g]   = Wih0[(g << 8) + hid];
        bb0v[g] = b0[(g << 8) + hid];
        bb1v[g] = b1[(g << 8) + hid];
    }
    const float outw_v = outW[hid];
    const float outb_v = outb[0];

    float c0r[16], c1r[16];
#pragma unroll
    for (int m = 0; m < 4; ++m)
#pragma unroll
        for (int r = 0; r < 4; ++r) {
            int grow = row0 + (wv << 6) + (m << 4) + (q << 2) + r;
            c0r[(m << 2) + r] = finc0[(size_t)(grow & 255) * HIDN + hid];
            c1r[(m << 2) + r] = finc1[(size_t)(grow & 255) * HIDN + hid];
        }

    unsigned int* fl = flags + (bt << 4);
    int dead = 0;

    for (int t = 0; t < 64; ++t) {
        const unsigned short* h0rd = h0buf + (size_t)(t & 1) * HP;        // h0(t-1); t=0 -> enc h0(512)
        unsigned short* h0wr       = h0buf + (size_t)((t + 1) & 1) * HP;
        const unsigned short* h1rd = h1buf + (size_t)((t + 1) & 1) * HP;  // h1(t-1); t=0 -> enc h1(512) @parity1
        unsigned short* h1wr       = h1buf + (size_t)(t & 1) * HP;
        float* pw       = predbuf + (t & 1) * DB;
        const float* pr = predbuf + ((t + 1) & 1) * DB;

        // pre: zero this step's pred accum; emit output column t-1
        if (hs == 0) {
            int n = row0 + tid;
            __hip_atomic_store((unsigned int*)&pw[n], 0u, __ATOMIC_RELAXED, __HIP_MEMORY_SCOPE_AGENT);
            if (t > 0) out[(size_t)(((n & 255) << 4) + (n >> 8)) * 64 + (t - 1)] = pr[n] + outb_v;
        }

        // ---- phase A: gates0 = h0(t-1) @ Whh0^T ----
        {
            float4v acc[4][4];
#pragma unroll
            for (int m = 0; m < 4; ++m)
#pragma unroll
                for (int g = 0; g < 4; ++g) acc[m][g] = (float4v){0,0,0,0};
            const unsigned short* pa[4];
#pragma unroll
            for (int m = 0; m < 4; ++m) {
                int ar = row0 + (wv << 6) + (m << 4) + l15;
                if (t == 0) ar &= 255;
                pa[m] = h0rd + (size_t)ar * HIDN + q8;
            }
#pragma unroll
            for (int kc = 0; kc < 8; ++kc) {
                short8v b0f = WFRAG(0, 0, kc), b1f = WFRAG(0, 1, kc);
                short8v b2f = WFRAG(0, 2, kc), b3f = WFRAG(0, 3, kc);
#pragma unroll
                for (int m = 0; m < 4; ++m) {
                    short8v a = *(const short8v*)&pa[m][kc << 5];
                    acc[m][0] = MFMA(a, b0f, acc[m][0]);
                    acc[m][1] = MFMA(a, b1f, acc[m][1]);
                    acc[m][2] = MFMA(a, b2f, acc[m][2]);
                    acc[m][3] = MFMA(a, b3f, acc[m][3]);
                }
            }
#pragma unroll
            for (int m = 0; m < 4; ++m)
#pragma unroll
                for (int r = 0; r < 4; ++r) {
                    int grow = row0 + (wv << 6) + (m << 4) + (q << 2) + r;
                    float inpv = (t == 0) ? dinit[grow] : (pr[grow] + outb_v);
                    float gi = acc[m][0][r] + wx[0] * inpv + bb0v[0];
                    float gf = acc[m][1][r] + wx[1] * inpv + bb0v[1];
                    float gg = acc[m][2][r] + wx[2] * inpv + bb0v[2];
                    float go = acc[m][3][r] + wx[3] * inpv + bb0v[3];
                    int ci = (m << 2) + r;
                    c0r[ci] = sigf(gf) * c0r[ci] + sigf(gi) * tanhf2(gg);
                    float h0n = sigf(go) * tanhf2(c0r[ci]);
                    hpair_store(h0wr, grow, hid, h0n, lane);
                }
        }
        __syncthreads();
        if (tid == 0)
            __hip_atomic_store(&fl[hs], (unsigned int)(2 * t + 1), __ATOMIC_RELAXED, __HIP_MEMORY_SCOPE_AGENT);
        group_wait(fl, (unsigned int)(2 * t + 1), lane, dead);

        // ---- phase B: gates1 = h0(t) @ Wih1^T + h1(t-1) @ Whh1^T ----
        {
            float4v acc[4][4];
#pragma unroll
            for (int m = 0; m < 4; ++m)
#pragma unroll
                for (int g = 0; g < 4; ++g) acc[m][g] = (float4v){0,0,0,0};
            const unsigned short* pa0[4];
            const unsigned short* pa1[4];
#pragma unroll
            for (int m = 0; m < 4; ++m) {
                int ar = row0 + (wv << 6) + (m << 4) + l15;
                pa0[m] = h0wr + (size_t)ar * HIDN + q8;
                int ar1 = (t == 0) ? (ar & 255) : ar;
                pa1[m] = h1rd + (size_t)ar1 * HIDN + q8;
            }
#pragma unroll
            for (int kc = 0; kc < 8; ++kc) {
                short8v b0f = WFRAG(1, 0, kc), b1f = WFRAG(1, 1, kc);
                short8v b2f = WFRAG(1, 2, kc), b3f = WFRAG(1, 3, kc);
#pragma unroll
                for (int m = 0; m < 4; ++m) {
                    short8v a = *(const short8v*)&pa0[m][kc << 5];
                    acc[m][0] = MFMA(a, b0f, acc[m][0]);
                    acc[m][1] = MFMA(a, b1f, acc[m][1]);
                    acc[m][2] = MFMA(a, b2f, acc[m][2]);
                    acc[m][3] = MFMA(a, b3f, acc[m][3]);
                }
            }
#pragma unroll
            for (int kc = 0; kc < 8; ++kc) {
                short8v b0f = WFRAG(2, 0, kc), b1f = WFRAG(2, 1, kc);
                short8v b2f = WFRAG(2, 2, kc), b3f = WFRAG(2, 3, kc);
#pragma unroll
                for (int m = 0; m < 4; ++m) {
                    short8v a = *(const short8v*)&pa1[m][kc << 5];
                    acc[m][0] = MFMA(a, b0f, acc[m][0]);
                    acc[m][1] = MFMA(a, b1f, acc[m][1]);
                    acc[m][2] = MFMA(a, b2f, acc[m][2]);
                    acc[m][3] = MFMA(a, b3f, acc[m][3]);
                }
            }
#pragma unroll
            for (int m = 0; m < 4; ++m)
#pragma unroll
                for (int r = 0; r < 4; ++r) {
                    int grow = row0 + (wv << 6) + (m << 4) + (q << 2) + r;
                    float gi = acc[m][0][r] + bb1v[0];
                    float gf = acc[m][1][r] + bb1v[1];
                    float gg = acc[m][2][r] + bb1v[2];
                    float go = acc[m][3][r] + bb1v[3];
                    int ci = (m << 2) + r;
                    c1r[ci] = sigf(gf) * c1r[ci] + sigf(gi) * tanhf2(gg);
                    float h1n = sigf(go) * tanhf2(c1r[ci]);
                    hpair_store(h1wr, grow, hid, h1n, lane);
                    float pp = h1n * outw_v;
                    pp += __shfl_xor(pp, 1);
                    pp += __shfl_xor(pp, 2);
                    pp += __shfl_xor(pp, 4);
                    pp += __shfl_xor(pp, 8);
                    if (l15 == 0) atomicAdd(&pw[grow], pp);
                }
        }
        __syncthreads();
        if (tid == 0)
            __hip_atomic_store(&fl[hs], (unsigned int)(2 * t + 2), __ATOMIC_RELAXED, __HIP_MEMORY_SCOPE_AGENT);
        group_wait(fl, (unsigned int)(2 * t + 2), lane, dead);
    }
    // tail: output column 63 (pred(63) lives at parity 1)
    if (hs == 0) {
        int n = row0 + tid;
        out[(size_t)(((n & 255) << 4) + (n >> 8)) * 64 + 63] = predbuf[DB + n] + outb_v;
    }
}

extern "C" void kernel_launch(void* const* d_in, const int* in_sizes, int n_in,
                              void* d_out, int out_size, void* d_ws, size_t ws_size,
                              hipStream_t stream) {
    (void)in_sizes; (void)n_in; (void)out_size; (void)ws_size;
    const float* x     = (const float*)d_in[0];
    const float* eWih0 = (const float*)d_in[1];
    const float* eWhh0 = (const float*)d_in[2];
    const float* eb0   = (const float*)d_in[3];
    const float* eWih1 = (const float*)d_in[4];
    const float* eWhh1 = (const float*)d_in[5];
    const float* eb1   = (const float*)d_in[6];
    const float* dWih0 = (const float*)d_in[7];
    const float* dWhh0 = (const float*)d_in[8];
    const float* db0   = (const float*)d_in[9];
    const float* dWih1 = (const float*)d_in[10];
    const float* dWhh1 = (const float*)d_in[11];
    const float* db1   = (const float*)d_in[12];
    const float* outW  = (const float*)d_in[13];
    const float* outb  = (const float*)d_in[14];
    const float* dinit = (const float*)d_in[15];

    char* ws = (char*)d_ws;
    unsigned short* h0buf = (unsigned short*)(ws);             // 4 MB
    unsigned short* h1buf = (unsigned short*)(ws + 4194304);   // 4 MB
    float* finc0          = (float*)(ws + 8388608);            // 256 KB
    float* finc1          = (float*)(ws + 8650752);            // 256 KB
    float* predbuf        = (float*)(ws + 8912896);            // 32 KB
    unsigned int* ctre    = (unsigned int*)(ws + 8945664);     // 16 groups x 16 u32
    unsigned int* ctrd    = (unsigned int*)(ws + 8946688);     // 16 groups x 16 u32

    hipMemsetAsync(ws + 8945664, 0, 2048, stream);
    hipFuncSetAttribute((const void*)dec_kernel,
                        hipFuncAttributeMaxDynamicSharedMemorySize, 98304);
    enc_kernel<<<256, 256, 0, stream>>>(x, eWih0, eWhh0, eb0, eWih1, eWhh1, eb1,
                                        h0buf, h1buf, finc0, finc1, ctre);
    dec_kernel<<<256, 256, 98304, stream>>>(dWih0, dWhh0, db0, dWih1, dWhh1, db1,
                                            outW, outb, dinit, finc0, finc1,
                                            h0buf, h1buf, predbuf, (float*)d_out, ctrd);
}

// Round 7
// 4825.236 us; speedup vs baseline: 6.8721x; 1.7165x over previous
//
#include <hip/hip_runtime.h>
#include <stdint.h>

// Seq2seq LSTM, f32 in/out, bf16 MFMA, fp32 cell state.
// R7 transport = R3-PROVEN primitives only:
//   h stores  : agent-scope relaxed atomic u32 (write-through to LLC)  [R3-proven]
//   barrier   : stores -> __syncthreads (vmcnt drain = stores complete at LLC)
//               -> agent flag store -> 16-lane agent relaxed poll      [R3-proven]
//   h reads   : agent-scope relaxed atomic u64 loads (LLC-fresh, bypass L1/L2
//               staleness) -- replaces R3's per-step agent-acquire buffer_inv
//               + plain reload (the suspected 10us/step overhead).
// No plain stores for shared data anywhere (R4/R5/R6 all failed on those).
// Encoder: 16 batch-groups(16 rows) x 16 hid-slices; weights in registers;
//   1 barrier/superstep (513); x staged in LDS; h slots 2-deep compact.
// Decoder: 16 batch-groups(256 rows) x 16 hid-slices; weights in 96KB LDS;
//   pred computed redundantly per block (no atomics); 2 barriers/step (128).

typedef short short8v __attribute__((ext_vector_type(8)));
typedef float float4v __attribute__((ext_vector_type(4)));
typedef unsigned long long u64;
#define MFMA(a,b,c) __builtin_amdgcn_mfma_f32_16x16x32_bf16((a),(b),(c),0,0,0)

#define HIDN 256
#define TLEN 512
#define DB   4096
#define HPE  ((size_t)256 * HIDN)    // enc h slot elements (128 KB)
#define HPD  ((size_t)DB * HIDN)     // dec h slot elements (2 MB)

__device__ __forceinline__ unsigned short f2b(float f) {
    unsigned int u = __float_as_uint(f);
    unsigned int r = ((u >> 16) & 1u) + 0x7FFFu;
    return (unsigned short)((u + r) >> 16);
}
__device__ __forceinline__ float b2f(unsigned short s) {
    return __uint_as_float(((unsigned int)s) << 16);
}
__device__ __forceinline__ float sigf(float x) { return 1.0f / (1.0f + __expf(-x)); }
__device__ __forceinline__ float tanhf2(float x) { return 1.0f - 2.0f / (1.0f + __expf(2.0f * x)); }

// 16B fragment as two agent-relaxed u64 atomic loads: always LLC-fresh.
__device__ __forceinline__ short8v ld_frag(const unsigned short* p) {
    union { short8v v; u64 q[2]; } u;
    u.q[0] = __hip_atomic_load((const u64*)p,       __ATOMIC_RELAXED, __HIP_MEMORY_SCOPE_AGENT);
    u.q[1] = __hip_atomic_load((const u64*)(p + 4), __ATOMIC_RELAXED, __HIP_MEMORY_SCOPE_AGENT);
    return u.v;
}

// pack 2 adjacent-hid bf16 via lane^1 shuffle; even lane does agent u32 store.
__device__ __forceinline__ void hpair_store(unsigned short* buf, int row, int hid,
                                            float h, int lane) {
    unsigned int mine = f2b(h);
    unsigned int part = (unsigned int)__shfl_xor((int)mine, 1);
    if (!(lane & 1)) {
        __hip_atomic_store((unsigned int*)&buf[(size_t)row * HIDN + hid],
                           mine | (part << 16),
                           __ATOMIC_RELAXED, __HIP_MEMORY_SCOPE_AGENT);
    }
}

// group barrier over 16 blocks; slots fl[0..15] (one 64B line); monotonic targets.
__device__ __forceinline__ void bar_sync(unsigned int* fl, int slot, unsigned int target,
                                         int lane, int tid, int& dead) {
    __syncthreads();   // vmcnt drain: this block's agent h stores complete at LLC
    if (tid == 0)
        __hip_atomic_store(&fl[slot], target, __ATOMIC_RELAXED, __HIP_MEMORY_SCOPE_AGENT);
    if (!dead) {
        int guard = 0;
        for (;;) {
            unsigned int v = 0xFFFFFFFFu;
            if (lane < 16)
                v = __hip_atomic_load(&fl[lane], __ATOMIC_RELAXED, __HIP_MEMORY_SCOPE_AGENT);
            if (__ballot(v >= target) == ~0ull) break;
            if (++guard > (1 << 20)) { dead = 1; break; }
        }
    }
    __builtin_amdgcn_fence(__ATOMIC_ACQUIRE, "workgroup");  // compiler ordering only
}

// ============================ ENCODER ============================
__global__ __launch_bounds__(256, 1) void enc_kernel(
    const float* __restrict__ x,
    const float* __restrict__ Wih0, const float* __restrict__ Whh0, const float* __restrict__ b0,
    const float* __restrict__ Wih1, const float* __restrict__ Whh1, const float* __restrict__ b1,
    unsigned short* __restrict__ h0e, unsigned short* __restrict__ h1e,   // [2][256][256]
    unsigned short* __restrict__ finh0, unsigned short* __restrict__ finh1,
    float* __restrict__ finc0, float* __restrict__ finc1,
    unsigned int* __restrict__ flags)
{
    const int tid = threadIdx.x, lane = tid & 63, wv = tid >> 6;
    const int bt = blockIdx.x & 15, hs = blockIdx.x >> 4;
    const int row0 = bt << 4, hidb = hs << 4;
    const int l15 = lane & 15, q = lane >> 4, q8 = q << 3;

    __shared__ float gt[12][16][17];
    __shared__ float xt[16][TLEN + 1];

    for (int idx = tid; idx < 16 * TLEN; idx += 256) {
        int r = idx >> 9, c = idx & 511;
        xt[r][c] = x[(size_t)(row0 + r) * TLEN + c];
    }

    // register weights: wave wv owns pairs p = wv*3+j, p=(mat*4+gate)
    short8v wf[3][8];
    {
        const float* Ws[3] = {Whh0, Wih1, Whh1};
#pragma unroll
        for (int j = 0; j < 3; ++j) {
            int p = wv * 3 + j;
            int mat = p >> 2, g = p & 3;
            const float* rp = Ws[mat] + (size_t)((g << 8) + hidb + l15) * HIDN + q8;
#pragma unroll
            for (int kc = 0; kc < 8; ++kc) {
                short8v v;
#pragma unroll
                for (int i = 0; i < 8; ++i) v[i] = (short)f2b(rp[(kc << 5) + i]);
                wf[j][kc] = v;
            }
        }
    }

    const int erow = tid >> 4, ehid = tid & 15;
    const int grow = row0 + erow, ghid = hidb + ehid;
    float wx[4], bb0v[4], bb1v[4];
#pragma unroll
    for (int g = 0; g < 4; ++g) {
        wx[g]   = Wih0[(g << 8) + ghid];
        bb0v[g] = b0[(g << 8) + ghid];
        bb1v[g] = b1[(g << 8) + ghid];
    }
    float c0 = 0.f, c1 = 0.f;
    unsigned int* fl = flags + (bt << 4);
    int dead = 0;
    const bool useH0 = (wv <= 2), useH1 = (wv >= 2);
    __syncthreads();   // xt ready

    for (int s = 1; s <= 513; ++s) {
        const unsigned short* hr0 = h0e + (size_t)((s - 1) & 1) * HPE;
        const unsigned short* hr1 = h1e + (size_t)((s - 1) & 1) * HPE;
        unsigned short* hw0 = h0e + (size_t)(s & 1) * HPE;
        unsigned short* hw1 = h1e + (size_t)(s & 1) * HPE;

        float4v acc[3] = {{0,0,0,0},{0,0,0,0},{0,0,0,0}};
        short8v a0f[8], a1f[8];
        if (useH0 && s >= 2) {
            const unsigned short* p0 = hr0 + (size_t)(row0 + l15) * HIDN + q8;
#pragma unroll
            for (int kc = 0; kc < 8; ++kc) a0f[kc] = ld_frag(&p0[kc << 5]);
        }
        if (useH1 && s >= 3) {
            const unsigned short* p1 = hr1 + (size_t)(row0 + l15) * HIDN + q8;
#pragma unroll
            for (int kc = 0; kc < 8; ++kc) a1f[kc] = ld_frag(&p1[kc << 5]);
        }
#pragma unroll
        for (int j = 0; j < 3; ++j) {
            int p = wv * 3 + j;
            int mat = p >> 2;
            bool active = (mat == 0) ? (s >= 2 && s <= 512)
                        : (mat == 1) ? (s >= 2)
                                     : (s >= 3);
            if (active) {
                if (mat == 2) {
#pragma unroll
                    for (int kc = 0; kc < 8; ++kc) acc[j] = MFMA(a1f[kc], wf[j][kc], acc[j]);
                } else {
#pragma unroll
                    for (int kc = 0; kc < 8; ++kc) acc[j] = MFMA(a0f[kc], wf[j][kc], acc[j]);
                }
            }
        }
#pragma unroll
        for (int j = 0; j < 3; ++j) {
            int p = wv * 3 + j;
#pragma unroll
            for (int r = 0; r < 4; ++r) gt[p][(q << 2) + r][l15] = acc[j][r];
        }
        __syncthreads();

        if (s <= 512) {
            float xv = xt[erow][s - 1];
            float gi = gt[0][erow][ehid] + wx[0] * xv + bb0v[0];
            float gf = gt[1][erow][ehid] + wx[1] * xv + bb0v[1];
            float gg = gt[2][erow][ehid] + wx[2] * xv + bb0v[2];
            float go = gt[3][erow][ehid] + wx[3] * xv + bb0v[3];
            c0 = sigf(gf) * c0 + sigf(gi) * tanhf2(gg);
            float h0n = sigf(go) * tanhf2(c0);
            hpair_store(hw0, grow, ghid, h0n, lane);
            if (s == 512) {
                finh0[(size_t)grow * HIDN + ghid] = f2b(h0n);
                finc0[(size_t)grow * HIDN + ghid] = c0;
            }
        }
        if (s >= 2) {
            float gi = gt[4][erow][ehid] + gt[8][erow][ehid]  + bb1v[0];
            float gf = gt[5][erow][ehid] + gt[9][erow][ehid]  + bb1v[1];
            float gg = gt[6][erow][ehid] + gt[10][erow][ehid] + bb1v[2];
            float go = gt[7][erow][ehid] + gt[11][erow][ehid] + bb1v[3];
            c1 = sigf(gf) * c1 + sigf(gi) * tanhf2(gg);
            float h1n = sigf(go) * tanhf2(c1);
            hpair_store(hw1, grow, ghid, h1n, lane);
            if (s == 513) {
                finh1[(size_t)grow * HIDN + ghid] = f2b(h1n);
                finc1[(size_t)grow * HIDN + ghid] = c1;
            }
        }
        bar_sync(fl, hs, (unsigned int)s, lane, tid, dead);
    }
}

// ============================ DECODER ============================
__global__ __launch_bounds__(256, 1) void dec_kernel(
    const float* __restrict__ Wih0, const float* __restrict__ Whh0, const float* __restrict__ b0,
    const float* __restrict__ Wih1, const float* __restrict__ Whh1, const float* __restrict__ b1,
    const float* __restrict__ outW, const float* __restrict__ outb,
    const float* __restrict__ dinit,
    const unsigned short* __restrict__ finh0, const unsigned short* __restrict__ finh1,
    const float* __restrict__ finc0, const float* __restrict__ finc1,
    unsigned short* __restrict__ h0d, unsigned short* __restrict__ h1d,  // [2][4096][256]
    float* __restrict__ out,
    unsigned int* __restrict__ flags)
{
    extern __shared__ unsigned short wlds[];   // 6144 frags * 16B = 96KB
    const int tid = threadIdx.x, lane = tid & 63, wv = tid >> 6;
    const int bt = blockIdx.x & 15, hs = blockIdx.x >> 4;
    const int row0 = bt << 8, hidb = hs << 4;
    const int l15 = lane & 15, q = lane >> 4, q8 = q << 3;
    const int hid = hidb + l15;

    for (int sl = tid; sl < 6144; sl += 256) {
        int mat = sl >> 11, g = (sl >> 9) & 3, kc = (sl >> 6) & 7, ln = sl & 63;
        const float* W = (mat == 0) ? Whh0 : ((mat == 1) ? Wih1 : Whh1);
        const float* p = W + (size_t)((g << 8) + hidb + (ln & 15)) * HIDN
                           + (kc << 5) + ((ln >> 4) << 3);
        short8v v;
#pragma unroll
        for (int i = 0; i < 8; ++i) v[i] = (short)f2b(p[i]);
        *(short8v*)&wlds[sl << 3] = v;
    }
#define WFRAG(mat, g, kc) (*(const short8v*)&wlds[((((((mat) << 2) + (g)) << 3) + (kc)) << 9) + (lane << 3)])

    float wxd[4], bb0d[4], bb1d[4];
#pragma unroll
    for (int g = 0; g < 4; ++g) {
        wxd[g]  = Wih0[(g << 8) + hid];
        bb0d[g] = b0[(g << 8) + hid];
        bb1d[g] = b1[(g << 8) + hid];
    }
    const float outb_v = outb[0];
    short8v wo8[8];   // out_W fragment matching A-layout k = kc*32+q8+i
#pragma unroll
    for (int kc = 0; kc < 8; ++kc)
#pragma unroll
        for (int i = 0; i < 8; ++i) wo8[kc][i] = (short)f2b(outW[(kc << 5) + q8 + i]);

    float c0r[16], c1r[16];
#pragma unroll
    for (int m = 0; m < 4; ++m)
#pragma unroll
        for (int r = 0; r < 4; ++r) {
            int grow = row0 + (wv << 6) + (m << 4) + (q << 2) + r;
            c0r[(m << 2) + r] = finc0[(size_t)(grow & 255) * HIDN + hid];
            c1r[(m << 2) + r] = finc1[(size_t)(grow & 255) * HIDN + hid];
        }

    unsigned int* fl = flags + (bt << 4);
    int dead = 0;
    __syncthreads();   // wlds ready

    for (int t = 0; t < 64; ++t) {
        unsigned short* h0wr = h0d + (size_t)(t & 1) * HPD;
        unsigned short* h1wr = h1d + (size_t)(t & 1) * HPD;

        // ---- phase A: layer1 Whh1 part + pred from h1(t-1); then layer0 ----
        float4v acc1[4][4];
        float predv[4];
        {
            short8v a1f[4][8];
#pragma unroll
            for (int m = 0; m < 4; ++m) {
                int ar = row0 + (wv << 6) + (m << 4) + l15;
                if (t == 0) {
                    const unsigned short* p1 = finh1 + (size_t)(ar & 255) * HIDN + q8;
#pragma unroll
                    for (int kc = 0; kc < 8; ++kc) a1f[m][kc] = *(const short8v*)&p1[kc << 5];
                } else {
                    const unsigned short* p1 = h1d + (size_t)((t - 1) & 1) * HPD
                                                   + (size_t)ar * HIDN + q8;
#pragma unroll
                    for (int kc = 0; kc < 8; ++kc) a1f[m][kc] = ld_frag(&p1[kc << 5]);
                }
            }
#pragma unroll
            for (int m = 0; m < 4; ++m)
#pragma unroll
                for (int g = 0; g < 4; ++g) acc1[m][g] = (float4v){0, 0, 0, 0};
#pragma unroll
            for (int kc = 0; kc < 8; ++kc) {
                short8v w0 = WFRAG(2, 0, kc), w1 = WFRAG(2, 1, kc);
                short8v w2 = WFRAG(2, 2, kc), w3 = WFRAG(2, 3, kc);
#pragma unroll
                for (int m = 0; m < 4; ++m) {
                    acc1[m][0] = MFMA(a1f[m][kc], w0, acc1[m][0]);
                    acc1[m][1] = MFMA(a1f[m][kc], w1, acc1[m][1]);
                    acc1[m][2] = MFMA(a1f[m][kc], w2, acc1[m][2]);
                    acc1[m][3] = MFMA(a1f[m][kc], w3, acc1[m][3]);
                }
            }
#pragma unroll
            for (int m = 0; m < 4; ++m) {
                float pp = 0.f;
#pragma unroll
                for (int kc = 0; kc < 8; ++kc)
#pragma unroll
                    for (int i = 0; i < 8; ++i)
                        pp += b2f((unsigned short)a1f[m][kc][i]) * b2f((unsigned short)wo8[kc][i]);
                pp += __shfl_xor(pp, 16);
                pp += __shfl_xor(pp, 32);
                predv[m] = pp;   // lane L holds pred of row (m<<4)+(L&15)
            }
        }
        if (hs == 0 && t > 0 && q == 0) {
#pragma unroll
            for (int m = 0; m < 4; ++m) {
                int rg = row0 + (wv << 6) + (m << 4) + l15;
                out[(size_t)(((rg & 255) << 4) + (rg >> 8)) * 64 + (t - 1)] = predv[m] + outb_v;
            }
        }
        {
            short8v a0f[4][8];
#pragma unroll
            for (int m = 0; m < 4; ++m) {
                int ar = row0 + (wv << 6) + (m << 4) + l15;
                if (t == 0) {
                    const unsigned short* p0 = finh0 + (size_t)(ar & 255) * HIDN + q8;
#pragma unroll
                    for (int kc = 0; kc < 8; ++kc) a0f[m][kc] = *(const short8v*)&p0[kc << 5];
                } else {
                    const unsigned short* p0 = h0d + (size_t)((t - 1) & 1) * HPD
                                                   + (size_t)ar * HIDN + q8;
#pragma unroll
                    for (int kc = 0; kc < 8; ++kc) a0f[m][kc] = ld_frag(&p0[kc << 5]);
                }
            }
            float4v acc0[4][4];
#pragma unroll
            for (int m = 0; m < 4; ++m)
#pragma unroll
                for (int g = 0; g < 4; ++g) acc0[m][g] = (float4v){0, 0, 0, 0};
#pragma unroll
            for (int kc = 0; kc < 8; ++kc) {
                short8v w0 = WFRAG(0, 0, kc), w1 = WFRAG(0, 1, kc);
                short8v w2 = WFRAG(0, 2, kc), w3 = WFRAG(0, 3, kc);
#pragma unroll
                for (int m = 0; m < 4; ++m) {
                    acc0[m][0] = MFMA(a0f[m][kc], w0, acc0[m][0]);
                    acc0[m][1] = MFMA(a0f[m][kc], w1, acc0[m][1]);
                    acc0[m][2] = MFMA(a0f[m][kc], w2, acc0[m][2]);
                    acc0[m][3] = MFMA(a0f[m][kc], w3, acc0[m][3]);
                }
            }
#pragma unroll
            for (int m = 0; m < 4; ++m)
#pragma unroll
                for (int r = 0; r < 4; ++r) {
                    int rg = row0 + (wv << 6) + (m << 4) + (q << 2) + r;
                    float inpv = (t == 0) ? dinit[rg]
                                          : (__shfl(predv[m], (q << 2) + r, 64) + outb_v);
                    float gi = acc0[m][0][r] + wxd[0] * inpv + bb0d[0];
                    float gf = acc0[m][1][r] + wxd[1] * inpv + bb0d[1];
                    float gg = acc0[m][2][r] + wxd[2] * inpv + bb0d[2];
                    float go = acc0[m][3][r] + wxd[3] * inpv + bb0d[3];
                    int ci = (m << 2) + r;
                    c0r[ci] = sigf(gf) * c0r[ci] + sigf(gi) * tanhf2(gg);
                    float h0n = sigf(go) * tanhf2(c0r[ci]);
                    hpair_store(h0wr, rg, hid, h0n, lane);
                }
        }
        bar_sync(fl, hs, (unsigned int)(2 * t + 1), lane, tid, dead);

        // ---- phase B: acc1 += h0(t) @ Wih1^T; epilogue ----
        {
            short8v a0w[4][8];
#pragma unroll
            for (int m = 0; m < 4; ++m) {
                int ar = row0 + (wv << 6) + (m << 4) + l15;
                const unsigned short* p0 = h0wr + (size_t)ar * HIDN + q8;
#pragma unroll
                for (int kc = 0; kc < 8; ++kc) a0w[m][kc] = ld_frag(&p0[kc << 5]);
            }
#pragma unroll
            for (int kc = 0; kc < 8; ++kc) {
                short8v w0 = WFRAG(1, 0, kc), w1 = WFRAG(1, 1, kc);
                short8v w2 = WFRAG(1, 2, kc), w3 = WFRAG(1, 3, kc);
#pragma unroll
                for (int m = 0; m < 4; ++m) {
                    acc1[m][0] = MFMA(a0w[m][kc], w0, acc1[m][0]);
                    acc1[m][1] = MFMA(a0w[m][kc], w1, acc1[m][1]);
                    acc1[m][2] = MFMA(a0w[m][kc], w2, acc1[m][2]);
                    acc1[m][3] = MFMA(a0w[m][kc], w3, acc1[m][3]);
                }
            }
#pragma unroll
            for (int m = 0; m < 4; ++m)
#pragma unroll
                for (int r = 0; r < 4; ++r) {
                    int rg = row0 + (wv << 6) + (m << 4) + (q << 2) + r;
                    float gi = acc1[m][0][r] + bb1d[0];
                    float gf = acc1[m][1][r] + bb1d[1];
                    float gg = acc1[m][2][r] + bb1d[2];
                    float go = acc1[m][3][r] + bb1d[3];
                    int ci = (m << 2) + r;
                    c1r[ci] = sigf(gf) * c1r[ci] + sigf(gi) * tanhf2(gg);
                    float h1n = sigf(go) * tanhf2(c1r[ci]);
                    hpair_store(h1wr, rg, hid, h1n, lane);
                }
        }
        bar_sync(fl, hs, (unsigned int)(2 * t + 2), lane, tid, dead);
    }
    // tail: pred(63) from h1(63) (slot 63&1 = 1), col 63
    if (hs == 0) {
        const unsigned short* h1f = h1d + HPD;
#pragma unroll
        for (int m = 0; m < 4; ++m) {
            int ar = row0 + (wv << 6) + (m << 4) + l15;
            const unsigned short* p1 = h1f + (size_t)ar * HIDN + q8;
            float pp = 0.f;
#pragma unroll
            for (int kc = 0; kc < 8; ++kc) {
                short8v a1 = ld_frag(&p1[kc << 5]);
#pragma unroll
                for (int i = 0; i < 8; ++i)
                    pp += b2f((unsigned short)a1[i]) * b2f((unsigned short)wo8[kc][i]);
            }
            pp += __shfl_xor(pp, 16);
            pp += __shfl_xor(pp, 32);
            if (q == 0)
                out[(size_t)(((ar & 255) << 4) + (ar >> 8)) * 64 + 63] = pp + outb_v;
        }
    }
}

extern "C" void kernel_launch(void* const* d_in, const int* in_sizes, int n_in,
                              void* d_out, int out_size, void* d_ws, size_t ws_size,
                              hipStream_t stream) {
    (void)in_sizes; (void)n_in; (void)out_size; (void)ws_size;
    const float* x     = (const float*)d_in[0];
    const float* eWih0 = (const float*)d_in[1];
    const float* eWhh0 = (const float*)d_in[2];
    const float* eb0   = (const float*)d_in[3];
    const float* eWih1 = (const float*)d_in[4];
    const float* eWhh1 = (const float*)d_in[5];
    const float* eb1   = (const float*)d_in[6];
    const float* dWih0 = (const float*)d_in[7];
    const float* dWhh0 = (const float*)d_in[8];
    const float* db0   = (const float*)d_in[9];
    const float* dWih1 = (const float*)d_in[10];
    const float* dWhh1 = (const float*)d_in[11];
    const float* db1   = (const float*)d_in[12];
    const float* outW  = (const float*)d_in[13];
    const float* outb  = (const float*)d_in[14];
    const float* dinit = (const float*)d_in[15];

    char* ws = (char*)d_ws;
    unsigned short* h0e   = (unsigned short*)(ws);              // 2*256*256*2 = 256 KB
    unsigned short* h1e   = (unsigned short*)(ws + 262144);     // 256 KB
    unsigned short* h0d   = (unsigned short*)(ws + 524288);     // 2*4096*256*2 = 4 MB
    unsigned short* h1d   = (unsigned short*)(ws + 4718592);    // 4 MB
    unsigned short* finh0 = (unsigned short*)(ws + 8912896);    // 128 KB
    unsigned short* finh1 = (unsigned short*)(ws + 9043968);    // 128 KB
    float* finc0          = (float*)(ws + 9175040);             // 256 KB
    float* finc1          = (float*)(ws + 9437184);             // 256 KB
    unsigned int* fle     = (unsigned int*)(ws + 9699328);      // 1 KB (16 grp x 16 slot)
    unsigned int* fld     = (unsigned int*)(ws + 9700352);      // 1 KB

    hipMemsetAsync(ws + 9699328, 0, 2048, stream);
    hipFuncSetAttribute((const void*)dec_kernel,
                        hipFuncAttributeMaxDynamicSharedMemorySize, 98304);
    enc_kernel<<<256, 256, 0, stream>>>(x, eWih0, eWhh0, eb0, eWih1, eWhh1, eb1,
                                        h0e, h1e, finh0, finh1, finc0, finc1, fle);
    dec_kernel<<<256, 256, 98304, stream>>>(dWih0, dWhh0, db0, dWih1, dWhh1, db1,
                                            outW, outb, dinit, finh0, finh1, finc0, finc1,
                                            h0d, h1d, (float*)d_out, fld);
}